// Round 13
// baseline (497.422 us; speedup 1.0000x reference)
//
#include <hip/hip_runtime.h>
#include <cstdint>
#include <cstddef>

typedef short short8 __attribute__((ext_vector_type(8)));
typedef float floatx4 __attribute__((ext_vector_type(4)));
typedef unsigned short u16;

__device__ __forceinline__ u16 f2bf(float f) {
    unsigned u = __float_as_uint(f);
    u += 0x7FFFu + ((u >> 16) & 1u);
    return (u16)(u >> 16);
}
__device__ __forceinline__ float bf2f(u16 h) {
    return __uint_as_float(((unsigned)h) << 16);
}

// async global->LDS, 16B per lane; LDS base must be wave-uniform.
__device__ __forceinline__ void gload_lds16(const u16* g, u16* l) {
    __builtin_amdgcn_global_load_lds(
        (const __attribute__((address_space(1))) void*)g,
        (__attribute__((address_space(3))) void*)l, 16, 0, 0);
}

// ---------------------------------------------------------------------------
// Kernel 1: x [4][72][32][32][32] f32 (NCDHW)  ->  xt [4][32][32][32][72] bf16
// ---------------------------------------------------------------------------
__global__ __launch_bounds__(256) void k_transpose_x(const float* __restrict__ x,
                                                     u16* __restrict__ xt) {
    __shared__ float tile[72 * 33];
    const int bx = blockIdx.x;               // ((b*32+d)*32+h)
    const int tid = threadIdx.x;
    const int b = bx >> 10, d = (bx >> 5) & 31, h = bx & 31;
    const float* src = x + (size_t)b * 72 * 32768 + d * 1024 + h * 32;
    for (int e = tid; e < 2304; e += 256) {
        int ci = e >> 5, w = e & 31;
        tile[ci * 33 + w] = src[(size_t)ci * 32768 + w];
    }
    __syncthreads();
    u16* dst = xt + (size_t)bx * 2304;
    for (int e = tid; e < 2304; e += 256) {
        int w = e / 72, ci = e - w * 72;
        dst[e] = f2bf(tile[ci * 33 + w]);
    }
}

// ---------------------------------------------------------------------------
// Kernel 2: W [176][72][5][5][5] f32 -> wt bf16 per-lane B-fragment layout:
//   wt[kd][kh][kblk(12)][nblk(11)][lane(64)][8]   (linear in kk = kh*12+kb)
//   k >= 360 tail is ZERO-FILLED (A-tail garbage must multiply 0).
// ---------------------------------------------------------------------------
__global__ __launch_bounds__(256) void k_prep_w(const float* __restrict__ W,
                                                u16* __restrict__ wt) {
    const int gid = blockIdx.x * 256 + threadIdx.x;   // 825*256 = 211200 = 3300 frags * 64
    const int frag = gid >> 6, lane = gid & 63;
    const int nb = frag % 11;
    int t = frag / 11;
    const int kb = t % 12;
    t = t / 12;
    const int kh = t % 5, kd = t / 5;
    const int n = lane & 15, q8 = (lane >> 4) * 8;
    const int co = nb * 16 + n;
    u16 v[8] __attribute__((aligned(16)));
    #pragma unroll
    for (int j = 0; j < 8; ++j) {
        int k = kb * 32 + q8 + j;
        u16 r = 0;
        if (k < 360) {
            int kw = k / 72, ci = k - kw * 72;
            r = f2bf(W[((size_t)co * 72 + ci) * 125 + kd * 25 + kh * 5 + kw]);
        }
        v[j] = r;
    }
    *(uint4*)(wt + (size_t)gid * 8) = *(const uint4*)v;
}

// ---------------------------------------------------------------------------
// Kernel 3: implicit-GEMM conv + fused gating.
// Two 4-wave barrier domains per CU (R12) + co-split (R5/R9) + register
// B-pipeline: step kk consumes B from REGISTERS (loaded from LDS slot kk%3
// during step kk-1), prefetches slot (kk+1)%3 -> regs under this step's
// MFMAs, and stages slot (kk+2)%3 via global_load_lds. All three slots are
// disjoint and every handoff crosses a barrier. Per-step LDS critical path
// drops from 13 reads to 4 A-reads; prefetch reads hide under 4*NF MFMAs.
// Co-split frees the registers this needs: acc 80/96 AGPR (vs 176), total
// ~190 regs/wave << 256.
// Grid 1024 = (b:4, d:32, ht:4, cb:2), bijective 8x128 XCD swizzle.
// cb0: frags nb {0,1,2,3, 9}   NF=5 ; cb1: frags nb {4,5,6,7,8,10} NF=6.
// LDS: A 12xLP (62,976 B) + 3 x NF*1024 B ring = 78,336 / 81,408 B -> 2/CU.
// ---------------------------------------------------------------------------
#define LP 2624
#define MFMA_BF16 __builtin_amdgcn_mfma_f32_16x16x32_bf16

template<int CB>
__device__ __forceinline__ void conv_body(const u16* __restrict__ xt,
                                          const u16* __restrict__ wt,
                                          const float* __restrict__ scalar_bias,
                                          const float* __restrict__ gate_bias,
                                          u16* __restrict__ zt,
                                          u16* sx, u16* sB,
                                          int b, int d, int h0,
                                          int tid, int lane, int wv,
                                          int c15, int q) {
    constexpr int NF = CB ? 6 : 5;
    constexpr int SLOT = NF * 512;            // u16 per ring slot

    floatx4 acc[4][NF];
    #pragma unroll
    for (int i = 0; i < 4; ++i) {
        #pragma unroll
        for (int j = 0; j < NF; ++j) acc[i][j] = (floatx4){0.f, 0.f, 0.f, 0.f};
    }

    const int laneA = c15 * 72 + q * 8;
    const u16* sxA = sx + 2 * wv * LP + laneA;
    short8 Bc[NF], Bn[NF];

    // stage the NF frags of kb-step kk_ into ring slot s_ (async, wave-split)
    auto stage = [&](int kk_, int s_) {
        const u16* gs_ = wt + (size_t)kk_ * 5632 + lane * 8;   // wt_kd pre-added by caller? no: use below
        (void)gs_;
    };
    (void)stage;

    for (int kd = 0; kd < 5; ++kd) {
        const int dp = d + kd - 2;
        if (dp < 0 || dp >= 32) continue;            // block-uniform
        const u16* wt_kd = wt + (size_t)kd * 5 * 67584;   // 12*11*512 u16 per (kd,kh)

        __syncthreads();   // all waves done with prev kd's sx/sB
        // ---- stage A d-slice into LDS (zero-fill halos & k-pad region) ----
        const u16* srcbase = xt + (size_t)((b * 32 + dp) * 32) * 2304;
        for (int idx = tid; idx < 12 * 328; idx += 256) {
            int r = idx / 328, c = idx - r * 328;
            int hp = h0 + r - 2;
            uint4 val = make_uint4(0u, 0u, 0u, 0u);
            if (hp >= 0 && hp < 32 && c >= 18 && c < 306)
                val = *(const uint4*)(srcbase + (size_t)hp * 2304 + (c * 8 - 144));
            *(uint4*)(&sx[r * LP + c * 8]) = val;
        }

        // ---- async-stage helper (NF chunks of 1024B over 4 waves) ----
        #define STAGE_SLOT(kk_, s_) do {                                            \
            const u16* gs_ = wt_kd + (size_t)(kk_) * 5632 + lane * 8;               \
            u16* ds_ = sB + (s_) * SLOT;                                            \
            {   const int nb0_ = CB ? (wv + 4) : ((wv == 4) ? 9 : wv);              \
                gload_lds16(gs_ + nb0_ * 512, ds_ + wv * 512); }                    \
            if (wv + 4 < NF) {                                                      \
                const int nb1_ = CB ? 10 : 9;   /* chunk wv+4 only when wv small */ \
                const int f1_  = wv + 4;                                            \
                const int nbx_ = CB ? ((f1_ == 5) ? 10 : (f1_ + 4))                 \
                                    : ((f1_ == 4) ? 9 : f1_);                       \
                (void)nb1_;                                                         \
                gload_lds16(gs_ + nbx_ * 512, ds_ + f1_ * 512);                     \
            }                                                                       \
        } while (0)

        STAGE_SLOT(0, 0);
        STAGE_SLOT(1, 1);
        __syncthreads();   // sx + slots 0,1 ready (implicit vmcnt/lgkm drain)

        // prologue: B for step 0 -> Bc registers
        {
            const u16* bp = sB + 0 * SLOT + lane * 8;
            #pragma unroll
            for (int f = 0; f < NF; ++f) Bc[f] = *(const short8*)(bp + f * 512);
        }

        int aoff = 0, kb = 0;   // aoff = kh*LP + kb*32
        // one kb-step: A reads, prefetch other reg-set from pslot, stage sslot,
        // then 4*NF MFMAs on the CUR set; barrier.
        #define STEP(CUR, NXT, kkc_, pslot_, sslot_) do {                           \
            const u16* ap_ = sxA + aoff;                                            \
            short8 A0_ = *(const short8*)(ap_);                                     \
            short8 A1_ = *(const short8*)(ap_ + 1152);                              \
            short8 A2_ = *(const short8*)(ap_ + LP);                                \
            short8 A3_ = *(const short8*)(ap_ + LP + 1152);                         \
            const u16* bp_ = sB + (pslot_) * SLOT + lane * 8;                       \
            _Pragma("unroll")                                                       \
            for (int f = 0; f < NF; ++f) NXT[f] = *(const short8*)(bp_ + f * 512);  \
            if ((kkc_) + 2 < 60) STAGE_SLOT((kkc_) + 2, (sslot_));                  \
            __builtin_amdgcn_s_setprio(1);                                          \
            _Pragma("unroll")                                                       \
            for (int f = 0; f < NF; ++f) {                                          \
                acc[0][f] = MFMA_BF16(A0_, CUR[f], acc[0][f], 0, 0, 0);             \
                acc[1][f] = MFMA_BF16(A1_, CUR[f], acc[1][f], 0, 0, 0);             \
                acc[2][f] = MFMA_BF16(A2_, CUR[f], acc[2][f], 0, 0, 0);             \
                acc[3][f] = MFMA_BF16(A3_, CUR[f], acc[3][f], 0, 0, 0);             \
            }                                                                       \
            __builtin_amdgcn_s_setprio(0);                                          \
            __syncthreads();                                                        \
            aoff += 32;                                                             \
            if (++kb == 12) { kb = 0; aoff += LP - 384; }                           \
        } while (0)

        #pragma unroll 1
        for (int m = 0; m < 10; ++m) {      // 10 x 6 steps; slots cycle 0,1,2
            const int kk0 = m * 6;
            STEP(Bc, Bn, kk0 + 0, 1, 2);
            STEP(Bn, Bc, kk0 + 1, 2, 0);
            STEP(Bc, Bn, kk0 + 2, 0, 1);
            STEP(Bn, Bc, kk0 + 3, 1, 2);
            STEP(Bc, Bn, kk0 + 4, 2, 0);
            STEP(Bn, Bc, kk0 + 5, 0, 1);
        }
        #undef STEP
        #undef STAGE_SLOT
    }

    // ---- epilogue: fused gate + bf16 store to zt (R5/R9-validated) ----
    // C/D layout: col(co within frag) = lane&15, row(pos) = q*4 + reg.
    constexpr int GF = NF - 1;                 // gate frag (nb 9 or 10)
    constexpr int NGATED = CB ? 5 : 3;
    int   slA[NGATED];
    float gbA[NGATED];
    #pragma unroll
    for (int j = 0; j < NGATED; ++j) {
        const int nb = CB ? (j + 4) : (j + 1);
        const int idx = (nb - 1) * 16 + c15;                 // co_f - 16
        const int mul = (nb <= 3) ? (idx / 3) : (16 + (idx - 48) / 5);
        slA[j] = (lane & 48) | (mul & 15);
        gbA[j] = gate_bias[mul];
    }
    const float sb = CB ? 0.f : scalar_bias[c15];
    #pragma unroll
    for (int mi = 0; mi < 4; ++mi) {
        const int hl = 2 * wv + (mi >> 1);
        const int wh = mi & 1;
        const size_t zrow0 = (size_t)((b * 32 + d) * 32 + (h0 + hl)) * 32;
        #pragma unroll
        for (int r = 0; r < 4; ++r) {
            const int w = wh * 16 + q * 4 + r;
            u16* zp = zt + (zrow0 + w) * 144;
            const float gv = acc[mi][GF][r];
            if (CB == 0)
                zp[c15] = f2bf(fmaxf(acc[mi][0][r] + sb, 0.f));  // scalar: relu+bias
            #pragma unroll
            for (int j = 0; j < NGATED; ++j) {
                const int nb = CB ? (j + 4) : (j + 1);
                float ys = __shfl(gv, slA[j], 64);
                float g  = 1.f / (1.f + __expf(-(ys + gbA[j])));
                zp[nb * 16 + c15] = f2bf(acc[mi][CB ? j : (j + 1)][r] * g);
            }
        }
    }
}

__global__ __launch_bounds__(256, 2) void k_conv(const u16* __restrict__ xt,
                                                 const u16* __restrict__ wt,
                                                 const float* __restrict__ scalar_bias,
                                                 const float* __restrict__ gate_bias,
                                                 u16* __restrict__ zt) {
    __shared__ __align__(16) u16 sx[12 * LP];       // 62,976 B
    __shared__ __align__(16) u16 sB[3 * 6 * 512];   // 18,432 B (cb1 size; cb0 uses less)
    const int bx = blockIdx.x;
    const int swz = (bx & 7) * 128 + (bx >> 3);     // 1024 = 8 XCD x 128, bijective
    const int cb = swz & 1, ht = (swz >> 1) & 3, d = (swz >> 3) & 31, b = swz >> 8;
    const int h0 = ht * 8;
    const int tid = threadIdx.x, lane = tid & 63, wv = tid >> 6;   // 4 waves
    const int c15 = lane & 15, q = lane >> 4;

    if (cb == 0)
        conv_body<0>(xt, wt, scalar_bias, gate_bias, zt, sx, sB, b, d, h0, tid, lane, wv, c15, q);
    else
        conv_body<1>(xt, wt, scalar_bias, gate_bias, zt, sx, sB, b, d, h0, tid, lane, wv, c15, q);
}

// ---------------------------------------------------------------------------
// Kernel 4a: separable Gaussian, d+h pass (stride 2 in d,h; w untouched).
// zt [4][32][32][32][144] bf16 -> tmp [b][od16][oh16][w32][144] f32.
// Index space: b(4) x od(16) x oh(16) x w(32) x c8(18) = 589,824 = 2304*256.
// ---------------------------------------------------------------------------
__global__ __launch_bounds__(256) void k_lowpass_dh(const u16* __restrict__ zt,
                                                    float* __restrict__ tmp) {
    const int gid = blockIdx.x * 256 + threadIdx.x;   // 2304*256 = 589,824
    const int c8 = gid % 18;
    int r = gid / 18;
    const int w  = r & 31; r >>= 5;
    const int oh = r & 15; r >>= 4;
    const int od = r & 15; r >>= 4;
    const int b  = r;
    const float lw[5] = {0.03208210f, 0.23705644f, 0.46172277f, 0.23705644f, 0.03208210f};
    float a[8];
    #pragma unroll
    for (int j = 0; j < 8; ++j) a[j] = 0.f;
    for (int kd = 0; kd < 5; ++kd) {
        const int dz = 2 * od + kd - 2;
        if (dz < 0 || dz >= 32) continue;
        for (int kh = 0; kh < 5; ++kh) {
            const int hz = 2 * oh + kh - 2;
            if (hz < 0 || hz >= 32) continue;
            const float wt2 = lw[kd] * lw[kh];
            const u16* p = zt + ((size_t)((b * 32 + dz) * 32 + hz) * 32 + w) * 144 + c8 * 8;
            u16 v[8] __attribute__((aligned(16)));
            *(uint4*)v = *(const uint4*)p;
            #pragma unroll
            for (int j = 0; j < 8; ++j) a[j] += wt2 * bf2f(v[j]);
        }
    }
    float* tp = tmp + ((size_t)(((b * 16 + od) * 16 + oh) * 32) + w) * 144 + c8 * 8;
    *(float4*)(tp)     = make_float4(a[0], a[1], a[2], a[3]);
    *(float4*)(tp + 4) = make_float4(a[4], a[5], a[6], a[7]);
}

// ---------------------------------------------------------------------------
// Kernel 4b: separable Gaussian, w pass (stride 2) + NCDHW transpose store.
// tmp [b][od][oh][w32][144] f32 -> out [4][144][16][16][16] f32.
// Index: b(4) x od(16) x oh(16) x ow(16) x c8(18) = 294,912 = 1152*256.
// ---------------------------------------------------------------------------
__global__ __launch_bounds__(256) void k_lowpass_w(const float* __restrict__ tmp,
                                                   float* __restrict__ out) {
    const int gid = blockIdx.x * 256 + threadIdx.x;   // 1152*256 = 294,912
    const int c8 = gid % 18;
    int r = gid / 18;
    const int ow = r & 15; r >>= 4;
    const int oh = r & 15; r >>= 4;
    const int od = r & 15; r >>= 4;
    const int b  = r;
    const float lw[5] = {0.03208210f, 0.23705644f, 0.46172277f, 0.23705644f, 0.03208210f};
    float a[8];
    #pragma unroll
    for (int j = 0; j < 8; ++j) a[j] = 0.f;
    const float* tb = tmp + ((size_t)(((b * 16 + od) * 16 + oh) * 32)) * 144 + c8 * 8;
    #pragma unroll
    for (int kw = 0; kw < 5; ++kw) {
        const int wz = 2 * ow + kw - 2;
        if (wz < 0 || wz >= 32) continue;
        const float wt1 = lw[kw];
        const float* p = tb + (size_t)wz * 144;
        float4 v0 = *(const float4*)(p);
        float4 v1 = *(const float4*)(p + 4);
        a[0] += wt1 * v0.x; a[1] += wt1 * v0.y; a[2] += wt1 * v0.z; a[3] += wt1 * v0.w;
        a[4] += wt1 * v1.x; a[5] += wt1 * v1.y; a[6] += wt1 * v1.z; a[7] += wt1 * v1.w;
    }
    const int c0 = c8 * 8;
    float* op = out + ((size_t)b * 144 + c0) * 4096 + od * 256 + oh * 16 + ow;
    #pragma unroll
    for (int j = 0; j < 8; ++j) op[(size_t)j * 4096] = a[j];
}

// ---------------------------------------------------------------------------
extern "C" void kernel_launch(void* const* d_in, const int* in_sizes, int n_in,
                              void* d_out, int out_size, void* d_ws, size_t ws_size,
                              hipStream_t stream) {
    const float* x  = (const float*)d_in[0];   // 4*72*32^3
    const float* W  = (const float*)d_in[1];   // 176*72*125
    const float* sb = (const float*)d_in[2];   // 16
    const float* gb = (const float*)d_in[3];   // 32
    float* out = (float*)d_out;                // 4*144*16^3 f32

    char* ws = (char*)d_ws;
    u16* xt = (u16*)(ws);                      // 18,874,368 B
    u16* wt = (u16*)(ws + 18874368);           //  3,379,200 B
    u16* zt = (u16*)(ws + 22253568);           // 37,748,736 B  (total ~60 MB)
    float* tmp = (float*)(ws);                 // reuses xt region after k_conv
                                               // (4*16*16*32*144*4 = 18,874,368 B, exact fit)

    hipLaunchKernelGGL(k_transpose_x, dim3(4096), dim3(256), 0, stream, x, xt);
    hipLaunchKernelGGL(k_prep_w,      dim3(825),  dim3(256), 0, stream, W, wt);
    hipLaunchKernelGGL(k_conv,        dim3(1024), dim3(256), 0, stream, xt, wt, sb, gb, zt);
    hipLaunchKernelGGL(k_lowpass_dh,  dim3(2304), dim3(256), 0, stream, zt, tmp);
    hipLaunchKernelGGL(k_lowpass_w,   dim3(1152), dim3(256), 0, stream, tmp, out);
}